// Round 13
// baseline (587.655 us; speedup 1.0000x reference)
//
#include <hip/hip_runtime.h>
#include <hip/hip_bf16.h>
#include <math.h>

// Problem constants
#define Bq 128
#define Nq 100
#define Dq 2048
#define Hq 1024
#define Oq 1600
#define Aq 400
#define Lq 2048
#define Mq (Bq * Nq)     // 12800 rows max
#define OqP 1664         // Oq padded to multiple of 128 (13 x 128)
#define AqP 512          // Aq padded to multiple of 128 (4 x 128)

typedef __attribute__((ext_vector_type(8))) short bf16x8;
typedef __attribute__((ext_vector_type(16))) float f32x16;
typedef unsigned short ushort;

// Fragment-major layout (32x32x16 MFMA operands):
//   chunk = rowtile(row/32) * KB + kb(k/16), KB = K/16
//   lane' = (row&31) + 32*((k>>3)&1), elem = k&7
//   addr  = chunk*512 + lane'*8 + elem
// One wave ds_read_b128/global-store at chunkbase + lane*16B == exact MFMA operand.

// ---------------- helpers ----------------
__device__ __forceinline__ void split1(float v, ushort& h, ushort& l) {
    __hip_bfloat16 bh = __float2bfloat16(v);          // RNE
    float fh = __bfloat162float(bh);
    __hip_bfloat16 bl = __float2bfloat16(v - fh);     // exact residual, then RNE
    h = __builtin_bit_cast(ushort, bh);
    l = __builtin_bit_cast(ushort, bl);
}

__device__ __forceinline__ void gl_lds16(const ushort* g, ushort* lds) {
    __builtin_amdgcn_global_load_lds(
        (const __attribute__((address_space(1))) unsigned int*)g,
        (__attribute__((address_space(3))) unsigned int*)lds,
        16, 0, 0);
}

// ------------- row compaction: offsets + rowmap (+ zero tile counters) -------------
__global__ void build_offsets(const int* __restrict__ num_descs,
                              int* __restrict__ off, int* __restrict__ mc,
                              int* __restrict__ rowmap, int* __restrict__ ctr)
{
    __shared__ int cnt[Bq];
    __shared__ int offs[Bq + 1];
    const int t = threadIdx.x;            // 0..127
    if (t < 3) ctr[t] = 0;                // dynamic-scheduling counters for 3 GEMMs
    int nd = num_descs[t];
    nd = nd < 0 ? 0 : (nd > Nq ? Nq : nd);
    const int c = nd < 1 ? 1 : nd;
    cnt[t] = c;
    __syncthreads();
    if (t == 0) {
        int s = 0;
        for (int i = 0; i < Bq; i++) { offs[i] = s; s += cnt[i]; }
        offs[Bq] = s;
        mc[0] = s;                          // Mc
        mc[1] = (s + 127) & ~127;           // McPad128
        mc[2] = (s + 255) & ~(int)255;      // McPad256 (BM=256 tiles + zero-fill)
    }
    __syncthreads();
    off[t] = offs[t];
    for (int i = t; i < Mq; i += Bq) rowmap[i] = -1;
    __syncthreads();
    const int o = offs[t];
    for (int n = 0; n < c; n++) rowmap[o + n] = t * Nq + n;
}

// -- gather + split x into compact hi/lo bf16, fragment-major --
// LDS-staged. Block covers rowtile rt x 64 cols: load phase is 256-B
// contiguous per 8-thread group; write phase 1 KB coalesced fragment-major
// stores. [32][66] pad -> <=2-way LDS bank alias on both phases (free, m136).
__global__ __launch_bounds__(256) void split_compact(const float* __restrict__ x,
                              const int* __restrict__ rowmap,
                              const int* __restrict__ mc,
                              ushort* __restrict__ hi, ushort* __restrict__ lo)
{
    const int KB = Dq / 16;                 // 128 chunks per row-tile
    const int nbc = Dq / 64;                // 32 col-groups
    const int rt = blockIdx.x / nbc;
    const int bc = (blockIdx.x - rt * nbc) * 64;
    if (rt * 32 >= mc[2]) return;           // zero-fill through 256-row padding

    __shared__ float t[32][66];
    const int tid = threadIdx.x;
    {
        const int row = tid >> 3;           // 0..31
        const int coff = (tid & 7) * 8;     // 0..56
        const int crow = rt * 32 + row;
        const int orig = (crow < mc[0]) ? rowmap[crow] : -1;
        float v[8];
        if (orig < 0) {
#pragma unroll
            for (int e = 0; e < 8; e++) v[e] = 0.f;
        } else {
            const float* src = x + (size_t)orig * Dq + bc + coff;
            float4 v0 = *(const float4*)(src);
            float4 v1 = *(const float4*)(src + 4);
            v[0] = v0.x; v[1] = v0.y; v[2] = v0.z; v[3] = v0.w;
            v[4] = v1.x; v[5] = v1.y; v[6] = v1.z; v[7] = v1.w;
        }
#pragma unroll
        for (int e = 0; e < 8; e++) t[row][coff + e] = v[e];
    }
    __syncthreads();

    const int wave = tid >> 6;              // chunk within the 64-col group
    const int lane = tid & 63;
    const int r32 = lane & 31;
    const int cl = wave * 16 + (lane >> 5) * 8;
    ushort h[8], l[8];
#pragma unroll
    for (int e = 0; e < 8; e++) split1(t[r32][cl + e], h[e], l[e]);
    const size_t wid = (size_t)rt * KB + (bc >> 4) + wave;
    const size_t a = wid * 512 + (size_t)lane * 8;
    *(bf16x8*)(hi + a) = *(bf16x8*)h;
    *(bf16x8*)(lo + a) = *(bf16x8*)l;
}

// --- batched transpose+split: W[K][N] -> fragment-major Wt_hi/lo over [Npad][K] ---
struct TSeg { const float* W; ushort* Th; ushort* Tl; int K; int N; int gx; int base; };
struct TSegs { TSeg s[6]; };

__global__ void tsplit_all(TSegs a)
{
    const int id = blockIdx.x;
    TSeg sg = a.s[5];
#pragma unroll
    for (int i = 4; i >= 0; i--) if (id < a.s[i + 1].base) sg = a.s[i];
    const int local = id - sg.base;
    const int bn = (local % sg.gx) * 32;
    const int bk = (local / sg.gx) * 32;
    const int KB = sg.K >> 4;

    __shared__ float t[32][33];   // t[k][n]
    const int tx = threadIdx.x & 31, ty = threadIdx.x >> 5;   // ty 0..7
#pragma unroll
    for (int i = 0; i < 4; i++) {
        const int k = bk + ty + i * 8, n = bn + tx;
        t[ty + i * 8][tx] = (n < sg.N) ? sg.W[(size_t)k * sg.N + n] : 0.f;
    }
    __syncthreads();

    // write phase: 4 waves; wave = (hl<<1)|kc ; lane covers (n&31, k-half)
    const int wave = threadIdx.x >> 6;
    const int lane = threadIdx.x & 63;
    const int kc = wave & 1;            // which 16-k chunk of the 32k tile
    const int hl = wave >> 1;           // 0 = hi, 1 = lo
    const int nloc = lane & 31;
    const int kloc = kc * 16 + (lane >> 5) * 8;
    ushort v8[8];
#pragma unroll
    for (int e = 0; e < 8; e++) {
        ushort h, l;
        split1(t[kloc + e][nloc], h, l);
        v8[e] = hl ? l : h;
    }
    const size_t chunk = (size_t)((bn >> 5)) * KB + (bk >> 4) + kc;
    ushort* dst = (hl ? sg.Tl : sg.Th) + chunk * 512 + (size_t)lane * 8;
    *(bf16x8*)dst = *(bf16x8*)v8;
}

// -------- split-bf16 MFMA GEMM: 32x32x16, fragment-major, conflict-free --------
// v13: r8's verified core (BM=256 x BN=128, 4 waves, 3-slot ring, vmcnt(6),
//      2 blocks/CU -- measured optimum of {tile, depth, occupancy, staging})
//      wrapped in DYNAMIC TILE SCHEDULING (persistent 512 blocks + atomic
//      counter). r12 accounting: static 800-tile/512-slot assignment = 1.56
//      rounds -> makespan 2 rounds = ~1.28x balanced time (L1 161 vs ~125 us
//      ideal). Work-stealing cuts imbalance to <=1 tile/slot (~0.6%).
//   idx -> (by = idx/nct, ct = idx%nct): ct-fastest, so the ~16 concurrent
//   grabs share one A-panel (temporal L2/L3 locality; XCD swizzle dropped --
//   meaningless under dynamic placement).
//   Inter-tile safety: loop-top __syncthreads after the grab -- every wave's
//   lgkm drained before its epilogue (MFMA scoreboard), so prior tile's LDS
//   reads are complete before the next tile's STAGE writes. Prologue vmcnt(6)
//   counts leftover epilogue stores too -- conservative, correct.
//   Per-tile schedule (unchanged from r8):
//     prologue: STAGE(0) STAGE(1) | vmcnt(6) | barrier
//     steady c: ds_read c | STAGE(c+2) | MFMA x24 | vmcnt(6) | lgkmcnt(0) | barrier
//     tails:    vmcnt(0), then none. Never 0 in the main loop (T4).
struct GArgs {
    const ushort* Ah; const ushort* Al;     // A fragment-major, K-chunks
    const ushort* Bh; const ushort* Bl;     // B fragment-major (weights, [Npad][K])
    const float* bias;
    float* Cf; ushort* Ch; ushort* Cl;      // outputs
    int K, Npad, Nreal, ldc, mode;          // mode 1: relu+split frag-major; 0: fp32 row-major
};

__global__ __launch_bounds__(256, 2) void gemm_split(GArgs g0, GArgs g1,
                                                     const int* __restrict__ mcp,
                                                     int nct0, int nct,
                                                     int* __restrict__ ctr)
{
    const int ny = mcp[2] >> 8;                  // active 256-row tiles
    const int nact = nct * ny;

    // 3-slot ring, 24 KB/slot: A-hi 8x512 | A-lo 8x512 | B-hi 4x512 | B-lo 4x512
    __shared__ __align__(16) ushort sAh[12288];
    __shared__ __align__(16) ushort sAl[12288];
    __shared__ __align__(16) ushort sBh[6144];
    __shared__ __align__(16) ushort sBl[6144];
    __shared__ int s_idx;

    const int tid  = threadIdx.x;
    const int wave = tid >> 6;           // 0..3
    const int lane = tid & 63;
    const int wm = wave >> 1;            // 0..1  (A base rowtile = wm*4)
    const int wn = wave & 1;             // 0..1  (B base rowtile = wn*2)
    const int l31  = lane & 31;
    const int half = lane >> 5;          // 0..1

    for (;;) {
        if (tid == 0) s_idx = atomicAdd(ctr, 1);
        __syncthreads();                 // broadcast idx + seal prior tile's LDS reads
        const int idx = s_idx;
        if (idx >= nact) return;
        const int by = idx / nct;
        const int ct = idx - by * nct;

        const GArgs g = (ct < nct0) ? g0 : g1;
        const int bm = by * 256;             // < mcp[2] by construction
        const int bn = (ct < nct0 ? ct : ct - nct0) * 128;
        const int KB = g.K >> 4;             // chunks along K (64 or 128 here)

        const ushort* gAh0 = g.Ah + ((size_t)(bm / 32 + wave) * KB) * 512 + lane * 8;
        const ushort* gAh1 = g.Ah + ((size_t)(bm / 32 + wave + 4) * KB) * 512 + lane * 8;
        const ushort* gAl0 = g.Al + ((size_t)(bm / 32 + wave) * KB) * 512 + lane * 8;
        const ushort* gAl1 = g.Al + ((size_t)(bm / 32 + wave + 4) * KB) * 512 + lane * 8;
        const ushort* gBh  = g.Bh + ((size_t)(bn / 32 + wave) * KB) * 512 + lane * 8;
        const ushort* gBl  = g.Bl + ((size_t)(bn / 32 + wave) * KB) * 512 + lane * 8;

        f32x16 acc[4][2] = {};

        // wave stages its 6 pieces of chunk c into slot c%3
        auto STAGE = [&](int c) {
            const size_t go = (size_t)c * 512;
            const int sa = (c % 3) * 4096;
            const int sb = (c % 3) * 2048;
            gl_lds16(gAh0 + go, &sAh[sa + (wave << 9)]);
            gl_lds16(gAh1 + go, &sAh[sa + ((wave + 4) << 9)]);
            gl_lds16(gAl0 + go, &sAl[sa + (wave << 9)]);
            gl_lds16(gAl1 + go, &sAl[sa + ((wave + 4) << 9)]);
            gl_lds16(gBh + go, &sBh[sb + (wave << 9)]);
            gl_lds16(gBl + go, &sBl[sb + (wave << 9)]);
        };

        // one pipeline phase; drain: 6 steady, 0 tail, -1 last (no wait/barrier)
        auto PHASE = [&](int c, int stage_c, int drain) {
            const int sa = (c % 3) * 4096;
            const int sb = (c % 3) * 2048;
            bf16x8 ah[4], al[4], bh[2], bl[2];
#pragma unroll
            for (int i = 0; i < 4; i++) {
                const int o = sa + (wm * 4 + i) * 512 + lane * 8;
                ah[i] = *(const bf16x8*)&sAh[o];
                al[i] = *(const bf16x8*)&sAl[o];
            }
#pragma unroll
            for (int j = 0; j < 2; j++) {
                const int o = sb + (wn * 2 + j) * 512 + lane * 8;
                bh[j] = *(const bf16x8*)&sBh[o];
                bl[j] = *(const bf16x8*)&sBl[o];
            }
            if (stage_c >= 0) STAGE(stage_c);    // writes slot (c-1)%3, sealed prev phase
            __builtin_amdgcn_s_setprio(1);
            // no manual lgkmcnt: compiler emits fine-grained lgkmcnt(N) per operand
#pragma unroll
            for (int i = 0; i < 4; i++)
#pragma unroll
                for (int j = 0; j < 2; j++) {
                    acc[i][j] = __builtin_amdgcn_mfma_f32_32x32x16_bf16(ah[i], bh[j], acc[i][j], 0, 0, 0);
                    acc[i][j] = __builtin_amdgcn_mfma_f32_32x32x16_bf16(ah[i], bl[j], acc[i][j], 0, 0, 0);
                    acc[i][j] = __builtin_amdgcn_mfma_f32_32x32x16_bf16(al[i], bh[j], acc[i][j], 0, 0, 0);
                }
            __builtin_amdgcn_s_setprio(0);
            if (drain == 6)      asm volatile("s_waitcnt vmcnt(6)" ::: "memory");
            else if (drain == 0) asm volatile("s_waitcnt vmcnt(0)" ::: "memory");
            if (drain >= 0) {
                asm volatile("s_waitcnt lgkmcnt(0)" ::: "memory");   // WAR seal
                asm volatile("s_barrier" ::: "memory");
            }
        };

        // prologue: fill 2 of 3 slots, wait for chunk 0 only (6 stay in flight)
        STAGE(0); STAGE(1);
        asm volatile("s_waitcnt vmcnt(6)" ::: "memory");
        asm volatile("s_barrier" ::: "memory");

        for (int c = 0; c < KB - 2; ++c) PHASE(c, c + 2, 6);
        PHASE(KB - 2, -1, 0);
        PHASE(KB - 1, -1, -1);

        // epilogue: C/D layout col=lane&31, row=(r&3)+8*(r>>2)+4*half (HW-verified r4)
        const int KC = g.ldc >> 4;
#pragma unroll
        for (int j = 0; j < 2; j++) {
            const int col = bn + (wn * 2 + j) * 32 + l31;
            if (col < g.Nreal) {
                const float bv = g.bias[col];
#pragma unroll
                for (int i = 0; i < 4; i++) {
#pragma unroll
                    for (int r = 0; r < 16; r++) {
                        const int row = bm + (wm * 4 + i) * 32 + (r & 3) + 8 * (r >> 2) + 4 * half;
                        float v = acc[i][j][r] + bv;
                        if (g.mode == 1) {
                            v = fmaxf(v, 0.f);
                            ushort h, l;
                            split1(v, h, l);
                            const size_t chunk = (size_t)(row >> 5) * KC + (col >> 4);
                            const size_t adr = chunk * 512
                                + (size_t)((row & 31) + 32 * ((col >> 3) & 1)) * 8 + (col & 7);
                            g.Ch[adr] = h;
                            g.Cl[adr] = l;
                        } else {
                            g.Cf[(size_t)row * g.ldc + col] = v;
                        }
                    }
                }
            }
        }
    }
}

// ------------- fused per-row softmax stats for both branches -------------
__global__ void softmax_stats2(const float* __restrict__ Zo, const float* __restrict__ Za,
                               const int* __restrict__ mc,
                               float* __restrict__ mxo, float* __restrict__ smo,
                               float* __restrict__ mxa, float* __restrict__ sma)
{
    const int r = blockIdx.x;
    if (r >= mc[0]) return;
    __shared__ float red[256];
    const int t = threadIdx.x;
#pragma unroll
    for (int br = 0; br < 2; br++) {
        const float* Z = br ? Za : Zo;
        const int ncols = br ? Aq : Oq;
        float* mx = br ? mxa : mxo;
        float* sm = br ? sma : smo;
        const float4* row = (const float4*)(Z + (size_t)r * ncols);
        const int n4 = ncols >> 2;
        float m = -INFINITY;
        for (int c = t; c < n4; c += 256) {
            const float4 v = row[c];
            m = fmaxf(m, fmaxf(fmaxf(v.x, v.y), fmaxf(v.z, v.w)));
        }
        red[t] = m;
        __syncthreads();
        for (int s = 128; s > 0; s >>= 1) {
            if (t < s) red[t] = fmaxf(red[t], red[t + s]);
            __syncthreads();
        }
        m = red[0];
        __syncthreads();
        float su = 0.f;
        for (int c = t; c < n4; c += 256) {
            const float4 v = row[c];
            su += expf(v.x - m) + expf(v.y - m) + expf(v.z - m) + expf(v.w - m);
        }
        red[t] = su;
        __syncthreads();
        for (int s = 128; s > 0; s >>= 1) {
            if (t < s) red[t] += red[t + s];
            __syncthreads();
        }
        if (t == 0) { mx[r] = m; sm[r] = red[0]; }
        __syncthreads();
    }
}

// ------------- fused argmax + output gather (one block per label) -------------
__global__ void argmax_gather(
    const float* __restrict__ Zo, const float* __restrict__ Za,
    const float* __restrict__ mxo, const float* __restrict__ smo,
    const float* __restrict__ mxa, const float* __restrict__ sma,
    const int* __restrict__ label_img, const int* __restrict__ num_descs,
    const int* __restrict__ obj_labels, const int* __restrict__ att_labels,
    const int* __restrict__ off, float* __restrict__ out)
{
    const int l = blockIdx.x;
    const int b = label_img[l];
    const int nd = num_descs[b];
    const int r0 = off[b];
    const int t = threadIdx.x;           // 0..255

    __shared__ float ss[128];
    __shared__ int   si[128];
    if (t < 128) {
        float score = -INFINITY;
        if (t < Nq && t < nd) {
            const int r = r0 + t;
            const float po = expf(Zo[(size_t)r * Oq + obj_labels[l]] - mxo[r]) / smo[r];
            const float pa = expf(Za[(size_t)r * Aq + att_labels[l]] - mxa[r]) / sma[r];
            score = po * pa;
        }
        ss[t] = score;
        si[t] = t;
    }
    __syncthreads();
    for (int s = 64; s > 0; s >>= 1) {
        if (t < s) {
            const float s2 = ss[t + s];
            const int   i2 = si[t + s];
            // first-max tie-break; all -inf -> index 0
            if (s2 > ss[t] || (s2 == ss[t] && i2 < si[t])) { ss[t] = s2; si[t] = i2; }
        }
        __syncthreads();
    }
    const int r = r0 + si[0];

    {
        const float mo = mxo[r];
        const float iso = 1.0f / smo[r];
        const float4* zo4 = (const float4*)(Zo + (size_t)r * Oq);
        float4* oo4 = (float4*)(out + (size_t)l * Oq);
        for (int c = t; c < (Oq >> 2); c += 256) {
            const float4 v = zo4[c];
            float4 w;
            w.x = expf(v.x - mo) * iso;
            w.y = expf(v.y - mo) * iso;
            w.z = expf(v.z - mo) * iso;
            w.w = expf(v.w - mo) * iso;
            oo4[c] = w;
        }
    }
    {
        const float ma = mxa[r];
        const float isa = 1.0f / sma[r];
        const float4* za4 = (const float4*)(Za + (size_t)r * Aq);
        float4* oa4 = (float4*)(out + (size_t)Lq * Oq + (size_t)l * Aq);
        for (int c = t; c < (Aq >> 2); c += 256) {
            const float4 v = za4[c];
            float4 w;
            w.x = expf(v.x - ma) * isa;
            w.y = expf(v.y - ma) * isa;
            w.z = expf(v.z - ma) * isa;
            w.w = expf(v.w - ma) * isa;
            oa4[c] = w;
        }
    }
}

extern "C" void kernel_launch(void* const* d_in, const int* in_sizes, int n_in,
                              void* d_out, int out_size, void* d_ws, size_t ws_size,
                              hipStream_t stream)
{
    const float* x          = (const float*)d_in[0];
    const int*   num_descs  = (const int*)d_in[1];
    const int*   label_img  = (const int*)d_in[2];
    const int*   obj_labels = (const int*)d_in[3];
    const int*   att_labels = (const int*)d_in[4];
    const float* w1o = (const float*)d_in[5];  const float* b1o = (const float*)d_in[6];
    const float* w2o = (const float*)d_in[7];  const float* b2o = (const float*)d_in[8];
    const float* w3o = (const float*)d_in[9];  const float* b3o = (const float*)d_in[10];
    const float* w1a = (const float*)d_in[11]; const float* b1a = (const float*)d_in[12];
    const float* w2a = (const float*)d_in[13]; const float* b2a = (const float*)d_in[14];
    const float* w3a = (const float*)d_in[15]; const float* b3a = (const float*)d_in[16];
    float* out = (float*)d_out;

    // ---- workspace carve with lifetime-based aliasing ----
    char* p = (char*)d_ws;
    auto carve = [&](size_t bytes) { char* q = p; p += (bytes + 255) & ~(size_t)255; return q; };

    char* bufA = carve((size_t)Mq * Dq * 2 * 2);            // xh|xl -> h2{o,a}{h,l}
    char* bufB = carve((size_t)Mq * Hq * 2 * 2 * 2);        // h1{o,a}{h,l} -> z3o|z3a
    ushort* w1oth = (ushort*)carve((size_t)Hq * Dq * 2);  ushort* w1otl = (ushort*)carve((size_t)Hq * Dq * 2);
    ushort* w1ath = (ushort*)carve((size_t)Hq * Dq * 2);  ushort* w1atl = (ushort*)carve((size_t)Hq * Dq * 2);
    ushort* w2oth = (ushort*)carve((size_t)Hq * Hq * 2);  ushort* w2otl = (ushort*)carve((size_t)Hq * Hq * 2);
    ushort* w2ath = (ushort*)carve((size_t)Hq * Hq * 2);  ushort* w2atl = (ushort*)carve((size_t)Hq * Hq * 2);
    ushort* w3oth = (ushort*)carve((size_t)OqP * Hq * 2); ushort* w3otl = (ushort*)carve((size_t)OqP * Hq * 2);
    ushort* w3ath = (ushort*)carve((size_t)AqP * Hq * 2); ushort* w3atl = (ushort*)carve((size_t)AqP * Hq * 2);
    float* mxo = (float*)carve(Mq * 4); float* smo = (float*)carve(Mq * 4);
    float* mxa = (float*)carve(Mq * 4); float* sma = (float*)carve(Mq * 4);
    int* off    = (int*)carve(Bq * 4);
    int* mc     = (int*)carve(4 * 4);
    int* rowmap = (int*)carve(Mq * 4);
    int* ctr    = (int*)carve(4 * 4);

    // aliased views
    ushort* xh = (ushort*)bufA;
    ushort* xl = xh + (size_t)Mq * Dq;
    ushort* h2oh = (ushort*)bufA;                    // x dead after L1
    ushort* h2ol = h2oh + (size_t)Mq * Hq;
    ushort* h2ah = h2ol + (size_t)Mq * Hq;
    ushort* h2al = h2ah + (size_t)Mq * Hq;
    ushort* h1oh = (ushort*)bufB;
    ushort* h1ol = h1oh + (size_t)Mq * Hq;
    ushort* h1ah = h1ol + (size_t)Mq * Hq;
    ushort* h1al = h1ah + (size_t)Mq * Hq;
    float* z3o = (float*)bufB;                       // h1 dead after L2
    float* z3a = z3o + (size_t)Mq * Oq;

    // ---- preprocessing ----
    build_offsets<<<1, 128, 0, stream>>>(num_descs, off, mc, rowmap, ctr);
    // block per (rowtile x 64-col group): LDS-staged coalesced gather+split
    split_compact<<<(Mq / 32) * (Dq / 64), 256, 0, stream>>>(x, rowmap, mc, xh, xl);

    {   // batched weight transpose+split (fragment-major): 6 segments, flat grid
        TSegs ts;
        int base = 0;
        auto seg = [&](const float* W, ushort* Th, ushort* Tl, int K, int N, int Npad) {
            TSeg s; s.W = W; s.Th = Th; s.Tl = Tl; s.K = K; s.N = N;
            s.gx = Npad / 32; s.base = base; base += (Npad / 32) * (K / 32); return s;
        };
        ts.s[0] = seg(w1o, w1oth, w1otl, Dq, Hq, Hq);
        ts.s[1] = seg(w1a, w1ath, w1atl, Dq, Hq, Hq);
        ts.s[2] = seg(w2o, w2oth, w2otl, Hq, Hq, Hq);
        ts.s[3] = seg(w2a, w2ath, w2atl, Hq, Hq, Hq);
        ts.s[4] = seg(w3o, w3oth, w3otl, Hq, Oq, OqP);
        ts.s[5] = seg(w3a, w3ath, w3atl, Hq, Aq, AqP);
        tsplit_all<<<base, 256, 0, stream>>>(ts);
    }

    // persistent 512-block GEMMs (2 blocks/CU x 256 CUs) with dynamic tile grab
    // ---- L1: h1 = relu(x @ w1 + b1), both branches fused ----
    {
        GArgs go = { xh, xl, w1oth, w1otl, b1o, nullptr, h1oh, h1ol, Dq, Hq, Hq, Hq, 1 };
        GArgs ga = { xh, xl, w1ath, w1atl, b1a, nullptr, h1ah, h1al, Dq, Hq, Hq, Hq, 1 };
        gemm_split<<<512, 256, 0, stream>>>(go, ga, mc, 8, 16, ctr + 0);
    }
    // ---- L2: h2 = relu(h1 @ w2 + b2) ----
    {
        GArgs go = { h1oh, h1ol, w2oth, w2otl, b2o, nullptr, h2oh, h2ol, Hq, Hq, Hq, Hq, 1 };
        GArgs ga = { h1ah, h1al, w2ath, w2atl, b2a, nullptr, h2ah, h2al, Hq, Hq, Hq, Hq, 1 };
        gemm_split<<<512, 256, 0, stream>>>(go, ga, mc, 8, 16, ctr + 1);
    }
    // ---- L3: z3 = h2 @ w3 + b3 (fp32 row-major out) ----
    {
        GArgs go = { h2oh, h2ol, w3oth, w3otl, b3o, z3o, nullptr, nullptr, Hq, OqP, Oq, Oq, 0 };
        GArgs ga = { h2ah, h2al, w3ath, w3atl, b3a, z3a, nullptr, nullptr, Hq, AqP, Aq, Aq, 0 };
        gemm_split<<<512, 256, 0, stream>>>(go, ga, mc, OqP / 128, OqP / 128 + AqP / 128, ctr + 2);
    }

    // ---- epilogue ----
    softmax_stats2<<<Mq, 256, 0, stream>>>(z3o, z3a, mc, mxo, smo, mxa, sma);
    argmax_gather<<<Lq, 256, 0, stream>>>(z3o, z3a, mxo, smo, mxa, sma,
                                          label_img, num_descs, obj_labels, att_labels, off, out);
}

// Round 14
// 543.481 us; speedup vs baseline: 1.0813x; 1.0813x over previous
//
#include <hip/hip_runtime.h>
#include <hip/hip_bf16.h>
#include <math.h>

// Problem constants
#define Bq 128
#define Nq 100
#define Dq 2048
#define Hq 1024
#define Oq 1600
#define Aq 400
#define Lq 2048
#define Mq (Bq * Nq)     // 12800 rows max
#define OqP 1664         // Oq padded to multiple of 128 (13 x 128)
#define AqP 512          // Aq padded to multiple of 128 (4 x 128)

typedef __attribute__((ext_vector_type(8))) short bf16x8;
typedef __attribute__((ext_vector_type(16))) float f32x16;
typedef unsigned short ushort;

// Fragment-major layout (32x32x16 MFMA operands):
//   chunk = rowtile(row/32) * KB + kb(k/16), KB = K/16
//   lane' = (row&31) + 32*((k>>3)&1), elem = k&7
//   addr  = chunk*512 + lane'*8 + elem
// One wave ds_read_b128/global-store at chunkbase + lane*16B == exact MFMA operand.

// ---------------- helpers ----------------
__device__ __forceinline__ void split1(float v, ushort& h, ushort& l) {
    __hip_bfloat16 bh = __float2bfloat16(v);          // RNE
    float fh = __bfloat162float(bh);
    __hip_bfloat16 bl = __float2bfloat16(v - fh);     // exact residual, then RNE
    h = __builtin_bit_cast(ushort, bh);
    l = __builtin_bit_cast(ushort, bl);
}

__device__ __forceinline__ void gl_lds16(const ushort* g, ushort* lds) {
    __builtin_amdgcn_global_load_lds(
        (const __attribute__((address_space(1))) unsigned int*)g,
        (__attribute__((address_space(3))) unsigned int*)lds,
        16, 0, 0);
}

// ------------- row compaction: offsets + rowmap -------------
__global__ void build_offsets(const int* __restrict__ num_descs,
                              int* __restrict__ off, int* __restrict__ mc,
                              int* __restrict__ rowmap)
{
    __shared__ int cnt[Bq];
    __shared__ int offs[Bq + 1];
    const int t = threadIdx.x;            // 0..127
    int nd = num_descs[t];
    nd = nd < 0 ? 0 : (nd > Nq ? Nq : nd);
    const int c = nd < 1 ? 1 : nd;
    cnt[t] = c;
    __syncthreads();
    if (t == 0) {
        int s = 0;
        for (int i = 0; i < Bq; i++) { offs[i] = s; s += cnt[i]; }
        offs[Bq] = s;
        mc[0] = s;                          // Mc
        mc[1] = (s + 127) & ~127;           // McPad128
        mc[2] = (s + 255) & ~(int)255;      // McPad256 (BM=256 tiles + zero-fill)
    }
    __syncthreads();
    off[t] = offs[t];
    for (int i = t; i < Mq; i += Bq) rowmap[i] = -1;
    __syncthreads();
    const int o = offs[t];
    for (int n = 0; n < c; n++) rowmap[o + n] = t * Nq + n;
}

// -- gather + split x into compact hi/lo bf16, fragment-major --
// LDS-staged. Block covers rowtile rt x 64 cols: load phase is 256-B
// contiguous per 8-thread group; write phase 1 KB coalesced fragment-major
// stores. [32][66] pad -> <=2-way LDS bank alias on both phases (free, m136).
__global__ __launch_bounds__(256) void split_compact(const float* __restrict__ x,
                              const int* __restrict__ rowmap,
                              const int* __restrict__ mc,
                              ushort* __restrict__ hi, ushort* __restrict__ lo)
{
    const int KB = Dq / 16;                 // 128 chunks per row-tile
    const int nbc = Dq / 64;                // 32 col-groups
    const int rt = blockIdx.x / nbc;
    const int bc = (blockIdx.x - rt * nbc) * 64;
    if (rt * 32 >= mc[2]) return;           // zero-fill through 256-row padding

    __shared__ float t[32][66];
    const int tid = threadIdx.x;
    {
        const int row = tid >> 3;           // 0..31
        const int coff = (tid & 7) * 8;     // 0..56
        const int crow = rt * 32 + row;
        const int orig = (crow < mc[0]) ? rowmap[crow] : -1;
        float v[8];
        if (orig < 0) {
#pragma unroll
            for (int e = 0; e < 8; e++) v[e] = 0.f;
        } else {
            const float* src = x + (size_t)orig * Dq + bc + coff;
            float4 v0 = *(const float4*)(src);
            float4 v1 = *(const float4*)(src + 4);
            v[0] = v0.x; v[1] = v0.y; v[2] = v0.z; v[3] = v0.w;
            v[4] = v1.x; v[5] = v1.y; v[6] = v1.z; v[7] = v1.w;
        }
#pragma unroll
        for (int e = 0; e < 8; e++) t[row][coff + e] = v[e];
    }
    __syncthreads();

    const int wave = tid >> 6;              // chunk within the 64-col group
    const int lane = tid & 63;
    const int r32 = lane & 31;
    const int cl = wave * 16 + (lane >> 5) * 8;
    ushort h[8], l[8];
#pragma unroll
    for (int e = 0; e < 8; e++) split1(t[r32][cl + e], h[e], l[e]);
    const size_t wid = (size_t)rt * KB + (bc >> 4) + wave;
    const size_t a = wid * 512 + (size_t)lane * 8;
    *(bf16x8*)(hi + a) = *(bf16x8*)h;
    *(bf16x8*)(lo + a) = *(bf16x8*)l;
}

// --- batched transpose+split: W[K][N] -> fragment-major Wt_hi/lo over [Npad][K] ---
struct TSeg { const float* W; ushort* Th; ushort* Tl; int K; int N; int gx; int base; };
struct TSegs { TSeg s[6]; };

__global__ void tsplit_all(TSegs a)
{
    const int id = blockIdx.x;
    TSeg sg = a.s[5];
#pragma unroll
    for (int i = 4; i >= 0; i--) if (id < a.s[i + 1].base) sg = a.s[i];
    const int local = id - sg.base;
    const int bn = (local % sg.gx) * 32;
    const int bk = (local / sg.gx) * 32;
    const int KB = sg.K >> 4;

    __shared__ float t[32][33];   // t[k][n]
    const int tx = threadIdx.x & 31, ty = threadIdx.x >> 5;   // ty 0..7
#pragma unroll
    for (int i = 0; i < 4; i++) {
        const int k = bk + ty + i * 8, n = bn + tx;
        t[ty + i * 8][tx] = (n < sg.N) ? sg.W[(size_t)k * sg.N + n] : 0.f;
    }
    __syncthreads();

    // write phase: 4 waves; wave = (hl<<1)|kc ; lane covers (n&31, k-half)
    const int wave = threadIdx.x >> 6;
    const int lane = threadIdx.x & 63;
    const int kc = wave & 1;            // which 16-k chunk of the 32k tile
    const int hl = wave >> 1;           // 0 = hi, 1 = lo
    const int nloc = lane & 31;
    const int kloc = kc * 16 + (lane >> 5) * 8;
    ushort v8[8];
#pragma unroll
    for (int e = 0; e < 8; e++) {
        ushort h, l;
        split1(t[kloc + e][nloc], h, l);
        v8[e] = hl ? l : h;
    }
    const size_t chunk = (size_t)((bn >> 5)) * KB + (bk >> 4) + kc;
    ushort* dst = (hl ? sg.Tl : sg.Th) + chunk * 512 + (size_t)lane * 8;
    *(bf16x8*)dst = *(bf16x8*)v8;
}

// -------- split-bf16 MFMA GEMM: 32x32x16, fragment-major, conflict-free --------
// v14 == r12 verbatim (measured optimum after 13 rounds of probing):
//   BM=256 x BN=128, 4 waves (2x2), wave owns 128x64 output, acc[4][2].
//   Per chunk: A 8 rowtiles + B 4 rowtiles, hi+lo = 24 KB; 3-slot ring = 72 KB
//   -> 2 blocks/CU. Static grid + runtime-active XCD-chunked swizzle.
//   Ledger: steady in-flight = chunks c+1,c+2 = 12 loads/wave; vmcnt(6)
//   retires c+1 only; tail 0 -> none. Never 0 in main loop (T4).
//   Phase: ds_read c (plain loads, compiler fine lgkmcnt) | STAGE(c+2) |
//   MFMA x24 | vmcnt(6) | lgkmcnt(0) (WAR seal) | s_barrier.
//   Probed-and-rejected: ring depth 2/4 (204/227 us), 3 blocks/CU (204),
//   reg-staging full/hybrid (222+, conservative compiler vmcnt re-serializes),
//   dynamic tile grab (173 -- per-tile drain counts epilogue stores, loses
//   XCD locality). This core is the optimum of that design space.
struct GArgs {
    const ushort* Ah; const ushort* Al;     // A fragment-major, K-chunks
    const ushort* Bh; const ushort* Bl;     // B fragment-major (weights, [Npad][K])
    const float* bias;
    float* Cf; ushort* Ch; ushort* Cl;      // outputs
    int K, Npad, Nreal, ldc, mode;          // mode 1: relu+split frag-major; 0: fp32 row-major
};

__global__ __launch_bounds__(256, 2) void gemm_split(GArgs g0, GArgs g1,
                                                     const int* __restrict__ mcp,
                                                     int nct0, int nct)
{
    // ---- runtime-active bijective XCD-chunked swizzle (m204) ----
    const int ny = mcp[2] >> 8;                  // active 256-row tiles
    const int nact = nct * ny;
    const int hw = blockIdx.x;
    if (hw >= nact) return;
    const int q = nact >> 3, r = nact & 7, xcd = hw & 7, pos = hw >> 3;
    const int L = (xcd < r ? xcd * (q + 1) : r * (q + 1) + (xcd - r) * q) + pos;
    const int by = L / nct;
    const int ct = L - by * nct;

    const GArgs g = (ct < nct0) ? g0 : g1;
    const int bm = by * 256;                 // < mcp[2] by construction
    const int bn = (ct < nct0 ? ct : ct - nct0) * 128;

    const int KB = g.K >> 4;                // chunks along K (64 or 128 here)

    // 3-slot ring, 24 KB/slot: A-hi 8x512 | A-lo 8x512 | B-hi 4x512 | B-lo 4x512
    __shared__ __align__(16) ushort sAh[12288];
    __shared__ __align__(16) ushort sAl[12288];
    __shared__ __align__(16) ushort sBh[6144];
    __shared__ __align__(16) ushort sBl[6144];

    const int tid  = threadIdx.x;
    const int wave = tid >> 6;           // 0..3
    const int lane = tid & 63;
    const int wm = wave >> 1;            // 0..1  (A base rowtile = wm*4)
    const int wn = wave & 1;             // 0..1  (B base rowtile = wn*2)
    const int l31  = lane & 31;
    const int half = lane >> 5;          // 0..1

    const ushort* gAh0 = g.Ah + ((size_t)(bm / 32 + wave) * KB) * 512 + lane * 8;
    const ushort* gAh1 = g.Ah + ((size_t)(bm / 32 + wave + 4) * KB) * 512 + lane * 8;
    const ushort* gAl0 = g.Al + ((size_t)(bm / 32 + wave) * KB) * 512 + lane * 8;
    const ushort* gAl1 = g.Al + ((size_t)(bm / 32 + wave + 4) * KB) * 512 + lane * 8;
    const ushort* gBh  = g.Bh + ((size_t)(bn / 32 + wave) * KB) * 512 + lane * 8;
    const ushort* gBl  = g.Bl + ((size_t)(bn / 32 + wave) * KB) * 512 + lane * 8;

    f32x16 acc[4][2] = {};

    // wave stages its 6 pieces of chunk c into slot c%3
    auto STAGE = [&](int c) {
        const size_t go = (size_t)c * 512;
        const int sa = (c % 3) * 4096;
        const int sb = (c % 3) * 2048;
        gl_lds16(gAh0 + go, &sAh[sa + (wave << 9)]);
        gl_lds16(gAh1 + go, &sAh[sa + ((wave + 4) << 9)]);
        gl_lds16(gAl0 + go, &sAl[sa + (wave << 9)]);
        gl_lds16(gAl1 + go, &sAl[sa + ((wave + 4) << 9)]);
        gl_lds16(gBh + go, &sBh[sb + (wave << 9)]);
        gl_lds16(gBl + go, &sBl[sb + (wave << 9)]);
    };

    // one pipeline phase; drain: 6 steady, 0 tail, -1 last (no wait/barrier)
    auto PHASE = [&](int c, int stage_c, int drain) {
        const int sa = (c % 3) * 4096;
        const int sb = (c % 3) * 2048;
        bf16x8 ah[4], al[4], bh[2], bl[2];
#pragma unroll
        for (int i = 0; i < 4; i++) {
            const int o = sa + (wm * 4 + i) * 512 + lane * 8;
            ah[i] = *(const bf16x8*)&sAh[o];
            al[i] = *(const bf16x8*)&sAl[o];
        }
#pragma unroll
        for (int j = 0; j < 2; j++) {
            const int o = sb + (wn * 2 + j) * 512 + lane * 8;
            bh[j] = *(const bf16x8*)&sBh[o];
            bl[j] = *(const bf16x8*)&sBl[o];
        }
        if (stage_c >= 0) STAGE(stage_c);        // writes slot (c-1)%3, sealed prev phase
        __builtin_amdgcn_s_setprio(1);
        // no manual lgkmcnt: compiler emits fine-grained lgkmcnt(N) per operand
        // (tracked plain loads), so MFMAs start on first operand arrival.
#pragma unroll
        for (int i = 0; i < 4; i++)
#pragma unroll
            for (int j = 0; j < 2; j++) {
                acc[i][j] = __builtin_amdgcn_mfma_f32_32x32x16_bf16(ah[i], bh[j], acc[i][j], 0, 0, 0);
                acc[i][j] = __builtin_amdgcn_mfma_f32_32x32x16_bf16(ah[i], bl[j], acc[i][j], 0, 0, 0);
                acc[i][j] = __builtin_amdgcn_mfma_f32_32x32x16_bf16(al[i], bh[j], acc[i][j], 0, 0, 0);
            }
        __builtin_amdgcn_s_setprio(0);
        if (drain == 6)      asm volatile("s_waitcnt vmcnt(6)" ::: "memory");
        else if (drain == 0) asm volatile("s_waitcnt vmcnt(0)" ::: "memory");
        if (drain >= 0) {
            asm volatile("s_waitcnt lgkmcnt(0)" ::: "memory");   // WAR seal before barrier
            asm volatile("s_barrier" ::: "memory");
        }
    };

    // prologue: fill 2 of 3 slots, wait for chunk 0 only (6 stay in flight)
    STAGE(0); STAGE(1);
    asm volatile("s_waitcnt vmcnt(6)" ::: "memory");
    asm volatile("s_barrier" ::: "memory");

    for (int c = 0; c < KB - 2; ++c) PHASE(c, c + 2, 6);
    PHASE(KB - 2, -1, 0);
    PHASE(KB - 1, -1, -1);

    // epilogue: C/D layout col=lane&31, row=(r&3)+8*(r>>2)+4*half (HW-verified r4)
    const int KC = g.ldc >> 4;
#pragma unroll
    for (int j = 0; j < 2; j++) {
        const int col = bn + (wn * 2 + j) * 32 + l31;
        if (col < g.Nreal) {
            const float bv = g.bias[col];
#pragma unroll
            for (int i = 0; i < 4; i++) {
#pragma unroll
                for (int r = 0; r < 16; r++) {
                    const int row = bm + (wm * 4 + i) * 32 + (r & 3) + 8 * (r >> 2) + 4 * half;
                    float v = acc[i][j][r] + bv;
                    if (g.mode == 1) {
                        v = fmaxf(v, 0.f);
                        ushort h, l;
                        split1(v, h, l);
                        const size_t chunk = (size_t)(row >> 5) * KC + (col >> 4);
                        const size_t adr = chunk * 512
                            + (size_t)((row & 31) + 32 * ((col >> 3) & 1)) * 8 + (col & 7);
                        g.Ch[adr] = h;
                        g.Cl[adr] = l;
                    } else {
                        g.Cf[(size_t)row * g.ldc + col] = v;
                    }
                }
            }
        }
    }
}

// ------------- fused per-row softmax stats for both branches -------------
__global__ void softmax_stats2(const float* __restrict__ Zo, const float* __restrict__ Za,
                               const int* __restrict__ mc,
                               float* __restrict__ mxo, float* __restrict__ smo,
                               float* __restrict__ mxa, float* __restrict__ sma)
{
    const int r = blockIdx.x;
    if (r >= mc[0]) return;
    __shared__ float red[256];
    const int t = threadIdx.x;
#pragma unroll
    for (int br = 0; br < 2; br++) {
        const float* Z = br ? Za : Zo;
        const int ncols = br ? Aq : Oq;
        float* mx = br ? mxa : mxo;
        float* sm = br ? sma : smo;
        const float4* row = (const float4*)(Z + (size_t)r * ncols);
        const int n4 = ncols >> 2;
        float m = -INFINITY;
        for (int c = t; c < n4; c += 256) {
            const float4 v = row[c];
            m = fmaxf(m, fmaxf(fmaxf(v.x, v.y), fmaxf(v.z, v.w)));
        }
        red[t] = m;
        __syncthreads();
        for (int s = 128; s > 0; s >>= 1) {
            if (t < s) red[t] = fmaxf(red[t], red[t + s]);
            __syncthreads();
        }
        m = red[0];
        __syncthreads();
        float su = 0.f;
        for (int c = t; c < n4; c += 256) {
            const float4 v = row[c];
            su += expf(v.x - m) + expf(v.y - m) + expf(v.z - m) + expf(v.w - m);
        }
        red[t] = su;
        __syncthreads();
        for (int s = 128; s > 0; s >>= 1) {
            if (t < s) red[t] += red[t + s];
            __syncthreads();
        }
        if (t == 0) { mx[r] = m; sm[r] = red[0]; }
        __syncthreads();
    }
}

// ------------- fused argmax + output gather (one block per label) -------------
__global__ void argmax_gather(
    const float* __restrict__ Zo, const float* __restrict__ Za,
    const float* __restrict__ mxo, const float* __restrict__ smo,
    const float* __restrict__ mxa, const float* __restrict__ sma,
    const int* __restrict__ label_img, const int* __restrict__ num_descs,
    const int* __restrict__ obj_labels, const int* __restrict__ att_labels,
    const int* __restrict__ off, float* __restrict__ out)
{
    const int l = blockIdx.x;
    const int b = label_img[l];
    const int nd = num_descs[b];
    const int r0 = off[b];
    const int t = threadIdx.x;           // 0..255

    __shared__ float ss[128];
    __shared__ int   si[128];
    if (t < 128) {
        float score = -INFINITY;
        if (t < Nq && t < nd) {
            const int r = r0 + t;
            const float po = expf(Zo[(size_t)r * Oq + obj_labels[l]] - mxo[r]) / smo[r];
            const float pa = expf(Za[(size_t)r * Aq + att_labels[l]] - mxa[r]) / sma[r];
            score = po * pa;
        }
        ss[t] = score;
        si[t] = t;
    }
    __syncthreads();
    for (int s = 64; s > 0; s >>= 1) {
        if (t < s) {
            const float s2 = ss[t + s];
            const int   i2 = si[t + s];
            // first-max tie-break; all -inf -> index 0
            if (s2 > ss[t] || (s2 == ss[t] && i2 < si[t])) { ss[t] = s2; si[t] = i2; }
        }
        __syncthreads();
    }
    const int r = r0 + si[0];

    {
        const float mo = mxo[r];
        const float iso = 1.0f / smo[r];
        const float4* zo4 = (const float4*)(Zo + (size_t)r * Oq);
        float4* oo4 = (float4*)(out + (size_t)l * Oq);
        for (int c = t; c < (Oq >> 2); c += 256) {
            const float4 v = zo4[c];
            float4 w;
            w.x = expf(v.x - mo) * iso;
            w.y = expf(v.y - mo) * iso;
            w.z = expf(v.z - mo) * iso;
            w.w = expf(v.w - mo) * iso;
            oo4[c] = w;
        }
    }
    {
        const float ma = mxa[r];
        const float isa = 1.0f / sma[r];
        const float4* za4 = (const float4*)(Za + (size_t)r * Aq);
        float4* oa4 = (float4*)(out + (size_t)Lq * Oq + (size_t)l * Aq);
        for (int c = t; c < (Aq >> 2); c += 256) {
            const float4 v = za4[c];
            float4 w;
            w.x = expf(v.x - ma) * isa;
            w.y = expf(v.y - ma) * isa;
            w.z = expf(v.z - ma) * isa;
            w.w = expf(v.w - ma) * isa;
            oa4[c] = w;
        }
    }
}

extern "C" void kernel_launch(void* const* d_in, const int* in_sizes, int n_in,
                              void* d_out, int out_size, void* d_ws, size_t ws_size,
                              hipStream_t stream)
{
    const float* x          = (const float*)d_in[0];
    const int*   num_descs  = (const int*)d_in[1];
    const int*   label_img  = (const int*)d_in[2];
    const int*   obj_labels = (const int*)d_in[3];
    const int*   att_labels = (const int*)d_in[4];
    const float* w1o = (const float*)d_in[5];  const float* b1o = (const float*)d_in[6];
    const float* w2o = (const float*)d_in[7];  const float* b2o = (const float*)d_in[8];
    const float* w3o = (const float*)d_in[9];  const float* b3o = (const float*)d_in[10];
    const float* w1a = (const float*)d_in[11]; const float* b1a = (const float*)d_in[12];
    const float* w2a = (const float*)d_in[13]; const float* b2a = (const float*)d_in[14];
    const float* w3a = (const float*)d_in[15]; const float* b3a = (const float*)d_in[16];
    float* out = (float*)d_out;

    // ---- workspace carve with lifetime-based aliasing ----
    char* p = (char*)d_ws;
    auto carve = [&](size_t bytes) { char* q = p; p += (bytes + 255) & ~(size_t)255; return q; };

    char* bufA = carve((size_t)Mq * Dq * 2 * 2);            // xh|xl -> h2{o,a}{h,l}
    char* bufB = carve((size_t)Mq * Hq * 2 * 2 * 2);        // h1{o,a}{h,l} -> z3o|z3a
    ushort* w1oth = (ushort*)carve((size_t)Hq * Dq * 2);  ushort* w1otl = (ushort*)carve((size_t)Hq * Dq * 2);
    ushort* w1ath = (ushort*)carve((size_t)Hq * Dq * 2);  ushort* w1atl = (ushort*)carve((size_t)Hq * Dq * 2);
    ushort* w2oth = (ushort*)carve((size_t)Hq * Hq * 2);  ushort* w2otl = (ushort*)carve((size_t)Hq * Hq * 2);
    ushort* w2ath = (ushort*)carve((size_t)Hq * Hq * 2);  ushort* w2atl = (ushort*)carve((size_t)Hq * Hq * 2);
    ushort* w3oth = (ushort*)carve((size_t)OqP * Hq * 2); ushort* w3otl = (ushort*)carve((size_t)OqP * Hq * 2);
    ushort* w3ath = (ushort*)carve((size_t)AqP * Hq * 2); ushort* w3atl = (ushort*)carve((size_t)AqP * Hq * 2);
    float* mxo = (float*)carve(Mq * 4); float* smo = (float*)carve(Mq * 4);
    float* mxa = (float*)carve(Mq * 4); float* sma = (float*)carve(Mq * 4);
    int* off    = (int*)carve(Bq * 4);
    int* mc     = (int*)carve(4 * 4);
    int* rowmap = (int*)carve(Mq * 4);

    // aliased views
    ushort* xh = (ushort*)bufA;
    ushort* xl = xh + (size_t)Mq * Dq;
    ushort* h2oh = (ushort*)bufA;                    // x dead after L1
    ushort* h2ol = h2oh + (size_t)Mq * Hq;
    ushort* h2ah = h2ol + (size_t)Mq * Hq;
    ushort* h2al = h2ah + (size_t)Mq * Hq;
    ushort* h1oh = (ushort*)bufB;
    ushort* h1ol = h1oh + (size_t)Mq * Hq;
    ushort* h1ah = h1ol + (size_t)Mq * Hq;
    ushort* h1al = h1ah + (size_t)Mq * Hq;
    float* z3o = (float*)bufB;                       // h1 dead after L2
    float* z3a = z3o + (size_t)Mq * Oq;

    // ---- preprocessing ----
    build_offsets<<<1, 128, 0, stream>>>(num_descs, off, mc, rowmap);
    // block per (rowtile x 64-col group): LDS-staged coalesced gather+split
    split_compact<<<(Mq / 32) * (Dq / 64), 256, 0, stream>>>(x, rowmap, mc, xh, xl);

    {   // batched weight transpose+split (fragment-major): 6 segments, flat grid
        TSegs ts;
        int base = 0;
        auto seg = [&](const float* W, ushort* Th, ushort* Tl, int K, int N, int Npad) {
            TSeg s; s.W = W; s.Th = Th; s.Tl = Tl; s.K = K; s.N = N;
            s.gx = Npad / 32; s.base = base; base += (Npad / 32) * (K / 32); return s;
        };
        ts.s[0] = seg(w1o, w1oth, w1otl, Dq, Hq, Hq);
        ts.s[1] = seg(w1a, w1ath, w1atl, Dq, Hq, Hq);
        ts.s[2] = seg(w2o, w2oth, w2otl, Hq, Hq, Hq);
        ts.s[3] = seg(w2a, w2ath, w2atl, Hq, Hq, Hq);
        ts.s[4] = seg(w3o, w3oth, w3otl, Hq, Oq, OqP);
        ts.s[5] = seg(w3a, w3ath, w3atl, Hq, Aq, AqP);
        tsplit_all<<<base, 256, 0, stream>>>(ts);
    }

    // flat 1D grids over (by x combined-ct); worst-case ny = Mq/256 = 50.
    // Kernel swizzles the runtime-active range (XCD-chunked, by outer -> A shared).
    // ---- L1: h1 = relu(x @ w1 + b1), both branches fused ----
    {
        GArgs go = { xh, xl, w1oth, w1otl, b1o, nullptr, h1oh, h1ol, Dq, Hq, Hq, Hq, 1 };
        GArgs ga = { xh, xl, w1ath, w1atl, b1a, nullptr, h1ah, h1al, Dq, Hq, Hq, Hq, 1 };
        gemm_split<<<16 * (Mq / 256), 256, 0, stream>>>(go, ga, mc, 8, 16);
    }
    // ---- L2: h2 = relu(h1 @ w2 + b2) ----
    {
        GArgs go = { h1oh, h1ol, w2oth, w2otl, b2o, nullptr, h2oh, h2ol, Hq, Hq, Hq, Hq, 1 };
        GArgs ga = { h1ah, h1al, w2ath, w2atl, b2a, nullptr, h2ah, h2al, Hq, Hq, Hq, Hq, 1 };
        gemm_split<<<16 * (Mq / 256), 256, 0, stream>>>(go, ga, mc, 8, 16);
    }
    // ---- L3: z3 = h2 @ w3 + b3 (fp32 row-major out) ----
    {
        GArgs go = { h2oh, h2ol, w3oth, w3otl, b3o, z3o, nullptr, nullptr, Hq, OqP, Oq, Oq, 0 };
        GArgs ga = { h2ah, h2al, w3ath, w3atl, b3a, z3a, nullptr, nullptr, Hq, AqP, Aq, Aq, 0 };
        gemm_split<<<(OqP / 128 + AqP / 128) * (Mq / 256), 256, 0, stream>>>(go, ga, mc,
                                                                            OqP / 128,
                                                                            OqP / 128 + AqP / 128);
    }

    // ---- epilogue ----
    softmax_stats2<<<Mq, 256, 0, stream>>>(z3o, z3a, mc, mxo, smo, mxa, sma);
    argmax_gather<<<Lq, 256, 0, stream>>>(z3o, z3a, mxo, smo, mxa, sma,
                                          label_img, num_descs, obj_labels, att_labels, off, out);
}

// Round 15
// 528.641 us; speedup vs baseline: 1.1116x; 1.0281x over previous
//
#include <hip/hip_runtime.h>
#include <hip/hip_bf16.h>
#include <math.h>

// Problem constants
#define Bq 128
#define Nq 100
#define Dq 2048
#define Hq 1024
#define Oq 1600
#define Aq 400
#define Lq 2048
#define Mq (Bq * Nq)     // 12800 rows max
#define OqP 1664         // Oq padded to multiple of 128 (13 x 128)
#define AqP 512          // Aq padded to multiple of 128 (4 x 128)

typedef __attribute__((ext_vector_type(8))) short bf16x8;
typedef __attribute__((ext_vector_type(16))) float f32x16;
typedef unsigned short ushort;

// Fragment-major layout (32x32x16 MFMA operands):
//   chunk = rowtile(row/32) * KB + kb(k/16), KB = K/16
//   lane' = (row&31) + 32*((k>>3)&1), elem = k&7
//   addr  = chunk*512 + lane'*8 + elem
// One wave ds_read_b128/global-store at chunkbase + lane*16B == exact MFMA operand.

// ---------------- helpers ----------------
__device__ __forceinline__ void split1(float v, ushort& h, ushort& l) {
    __hip_bfloat16 bh = __float2bfloat16(v);          // RNE
    float fh = __bfloat162float(bh);
    __hip_bfloat16 bl = __float2bfloat16(v - fh);     // exact residual, then RNE
    h = __builtin_bit_cast(ushort, bh);
    l = __builtin_bit_cast(ushort, bl);
}

__device__ __forceinline__ void gl_lds16(const ushort* g, ushort* lds) {
    __builtin_amdgcn_global_load_lds(
        (const __attribute__((address_space(1))) unsigned int*)g,
        (__attribute__((address_space(3))) unsigned int*)lds,
        16, 0, 0);
}

// ------------- row compaction: offsets + rowmap -------------
__global__ void build_offsets(const int* __restrict__ num_descs,
                              int* __restrict__ off, int* __restrict__ mc,
                              int* __restrict__ rowmap)
{
    __shared__ int cnt[Bq];
    __shared__ int offs[Bq + 1];
    const int t = threadIdx.x;            // 0..127
    int nd = num_descs[t];
    nd = nd < 0 ? 0 : (nd > Nq ? Nq : nd);
    const int c = nd < 1 ? 1 : nd;
    cnt[t] = c;
    __syncthreads();
    if (t == 0) {
        int s = 0;
        for (int i = 0; i < Bq; i++) { offs[i] = s; s += cnt[i]; }
        offs[Bq] = s;
        mc[0] = s;                          // Mc
        mc[1] = (s + 127) & ~127;           // McPad128
        mc[2] = (s + 255) & ~(int)255;      // McPad256 (BM=256 tiles + zero-fill)
    }
    __syncthreads();
    off[t] = offs[t];
    for (int i = t; i < Mq; i += Bq) rowmap[i] = -1;
    __syncthreads();
    const int o = offs[t];
    for (int n = 0; n < c; n++) rowmap[o + n] = t * Nq + n;
}

// --- merged preprocessing: x gather+split AND weight transpose+split in ONE
//     dispatch (both BW-bound + independent; serial launches wasted a ramp).
//     Blocks [0, nsplit): split_compact body. Blocks [nsplit, ...): tsplit body.
struct TSeg { const float* W; ushort* Th; ushort* Tl; int K; int N; int gx; int base; };
struct TSegs { TSeg s[6]; };

__global__ __launch_bounds__(256) void prep_all(
    const float* __restrict__ x, const int* __restrict__ rowmap,
    const int* __restrict__ mc, ushort* __restrict__ hi, ushort* __restrict__ lo,
    TSegs a, int nsplit)
{
    __shared__ float sm[32 * 66];           // union: split uses 32x66, tsplit 32x33
    const int tid = threadIdx.x;

    if ((int)blockIdx.x < nsplit) {
        // ---- gather + split x (LDS-staged, coalesced; [32][66] pad <=2-way) ----
        const int KB = Dq / 16;             // 128 chunks per row-tile
        const int nbc = Dq / 64;            // 32 col-groups
        const int rt = blockIdx.x / nbc;
        const int bc = (blockIdx.x - rt * nbc) * 64;
        if (rt * 32 >= mc[2]) return;       // zero-fill through 256-row padding
        {
            const int row = tid >> 3;       // 0..31
            const int coff = (tid & 7) * 8; // 0..56
            const int crow = rt * 32 + row;
            const int orig = (crow < mc[0]) ? rowmap[crow] : -1;
            float v[8];
            if (orig < 0) {
#pragma unroll
                for (int e = 0; e < 8; e++) v[e] = 0.f;
            } else {
                const float* src = x + (size_t)orig * Dq + bc + coff;
                float4 v0 = *(const float4*)(src);
                float4 v1 = *(const float4*)(src + 4);
                v[0] = v0.x; v[1] = v0.y; v[2] = v0.z; v[3] = v0.w;
                v[4] = v1.x; v[5] = v1.y; v[6] = v1.z; v[7] = v1.w;
            }
#pragma unroll
            for (int e = 0; e < 8; e++) sm[row * 66 + coff + e] = v[e];
        }
        __syncthreads();

        const int wave = tid >> 6;          // chunk within the 64-col group
        const int lane = tid & 63;
        const int r32 = lane & 31;
        const int cl = wave * 16 + (lane >> 5) * 8;
        ushort h[8], l[8];
#pragma unroll
        for (int e = 0; e < 8; e++) split1(sm[r32 * 66 + cl + e], h[e], l[e]);
        const size_t wid = (size_t)rt * KB + (bc >> 4) + wave;
        const size_t ad = wid * 512 + (size_t)lane * 8;
        *(bf16x8*)(hi + ad) = *(bf16x8*)h;
        *(bf16x8*)(lo + ad) = *(bf16x8*)l;
    } else {
        // ---- batched weight transpose+split (fragment-major) ----
        const int id = blockIdx.x - nsplit;
        TSeg sg = a.s[5];
#pragma unroll
        for (int i = 4; i >= 0; i--) if (id < a.s[i + 1].base) sg = a.s[i];
        const int local = id - sg.base;
        const int bn = (local % sg.gx) * 32;
        const int bk = (local / sg.gx) * 32;
        const int KB = sg.K >> 4;

        const int tx = tid & 31, ty = tid >> 5;   // ty 0..7
#pragma unroll
        for (int i = 0; i < 4; i++) {
            const int k = bk + ty + i * 8, n = bn + tx;
            sm[(ty + i * 8) * 33 + tx] = (n < sg.N) ? sg.W[(size_t)k * sg.N + n] : 0.f;
        }
        __syncthreads();

        // write phase: 4 waves; wave = (hl<<1)|kc ; lane covers (n&31, k-half)
        const int wave = tid >> 6;
        const int lane = tid & 63;
        const int kc = wave & 1;            // which 16-k chunk of the 32k tile
        const int hl = wave >> 1;           // 0 = hi, 1 = lo
        const int nloc = lane & 31;
        const int kloc = kc * 16 + (lane >> 5) * 8;
        ushort v8[8];
#pragma unroll
        for (int e = 0; e < 8; e++) {
            ushort h, l;
            split1(sm[(kloc + e) * 33 + nloc], h, l);
            v8[e] = hl ? l : h;
        }
        const size_t chunk = (size_t)((bn >> 5)) * KB + (bk >> 4) + kc;
        ushort* dst = (hl ? sg.Tl : sg.Th) + chunk * 512 + (size_t)lane * 8;
        *(bf16x8*)dst = *(bf16x8*)v8;
    }
}

// -------- split-bf16 MFMA GEMM: 32x32x16, fragment-major, conflict-free --------
// r12/r14 verbatim (measured optimum after 14 rounds of probing):
//   BM=256 x BN=128, 4 waves (2x2), wave owns 128x64 output, acc[4][2].
//   Per chunk: A 8 rowtiles + B 4 rowtiles, hi+lo = 24 KB; 3-slot ring = 72 KB
//   -> 2 blocks/CU. Static grid + runtime-active XCD-chunked swizzle.
//   Ledger: steady in-flight = chunks c+1,c+2 = 12 loads/wave; vmcnt(6)
//   retires c+1 only; tail 0 -> none. Never 0 in main loop (T4).
//   Phase: ds_read c (plain loads, compiler fine lgkmcnt) | STAGE(c+2) |
//   MFMA x24 | vmcnt(6) | lgkmcnt(0) (WAR seal) | s_barrier.
//   Probed-and-rejected: ring depth 2/4 (204/227 us), 3 blocks/CU (204),
//   reg-staging full/hybrid (222+), dynamic tile grab (173).
struct GArgs {
    const ushort* Ah; const ushort* Al;     // A fragment-major, K-chunks
    const ushort* Bh; const ushort* Bl;     // B fragment-major (weights, [Npad][K])
    const float* bias;
    float* Cf; ushort* Ch; ushort* Cl;      // outputs
    int K, Npad, Nreal, ldc, mode;          // mode 1: relu+split frag-major; 0: fp32 row-major
};

__global__ __launch_bounds__(256, 2) void gemm_split(GArgs g0, GArgs g1,
                                                     const int* __restrict__ mcp,
                                                     int nct0, int nct)
{
    // ---- runtime-active bijective XCD-chunked swizzle (m204) ----
    const int ny = mcp[2] >> 8;                  // active 256-row tiles
    const int nact = nct * ny;
    const int hw = blockIdx.x;
    if (hw >= nact) return;
    const int q = nact >> 3, r = nact & 7, xcd = hw & 7, pos = hw >> 3;
    const int L = (xcd < r ? xcd * (q + 1) : r * (q + 1) + (xcd - r) * q) + pos;
    const int by = L / nct;
    const int ct = L - by * nct;

    const GArgs g = (ct < nct0) ? g0 : g1;
    const int bm = by * 256;                 // < mcp[2] by construction
    const int bn = (ct < nct0 ? ct : ct - nct0) * 128;

    const int KB = g.K >> 4;                // chunks along K (64 or 128 here)

    // 3-slot ring, 24 KB/slot: A-hi 8x512 | A-lo 8x512 | B-hi 4x512 | B-lo 4x512
    __shared__ __align__(16) ushort sAh[12288];
    __shared__ __align__(16) ushort sAl[12288];
    __shared__ __align__(16) ushort sBh[6144];
    __shared__ __align__(16) ushort sBl[6144];

    const int tid  = threadIdx.x;
    const int wave = tid >> 6;           // 0..3
    const int lane = tid & 63;
    const int wm = wave >> 1;            // 0..1  (A base rowtile = wm*4)
    const int wn = wave & 1;             // 0..1  (B base rowtile = wn*2)
    const int l31  = lane & 31;
    const int half = lane >> 5;          // 0..1

    const ushort* gAh0 = g.Ah + ((size_t)(bm / 32 + wave) * KB) * 512 + lane * 8;
    const ushort* gAh1 = g.Ah + ((size_t)(bm / 32 + wave + 4) * KB) * 512 + lane * 8;
    const ushort* gAl0 = g.Al + ((size_t)(bm / 32 + wave) * KB) * 512 + lane * 8;
    const ushort* gAl1 = g.Al + ((size_t)(bm / 32 + wave + 4) * KB) * 512 + lane * 8;
    const ushort* gBh  = g.Bh + ((size_t)(bn / 32 + wave) * KB) * 512 + lane * 8;
    const ushort* gBl  = g.Bl + ((size_t)(bn / 32 + wave) * KB) * 512 + lane * 8;

    f32x16 acc[4][2] = {};

    // wave stages its 6 pieces of chunk c into slot c%3
    auto STAGE = [&](int c) {
        const size_t go = (size_t)c * 512;
        const int sa = (c % 3) * 4096;
        const int sb = (c % 3) * 2048;
        gl_lds16(gAh0 + go, &sAh[sa + (wave << 9)]);
        gl_lds16(gAh1 + go, &sAh[sa + ((wave + 4) << 9)]);
        gl_lds16(gAl0 + go, &sAl[sa + (wave << 9)]);
        gl_lds16(gAl1 + go, &sAl[sa + ((wave + 4) << 9)]);
        gl_lds16(gBh + go, &sBh[sb + (wave << 9)]);
        gl_lds16(gBl + go, &sBl[sb + (wave << 9)]);
    };

    // one pipeline phase; drain: 6 steady, 0 tail, -1 last (no wait/barrier)
    auto PHASE = [&](int c, int stage_c, int drain) {
        const int sa = (c % 3) * 4096;
        const int sb = (c % 3) * 2048;
        bf16x8 ah[4], al[4], bh[2], bl[2];
#pragma unroll
        for (int i = 0; i < 4; i++) {
            const int o = sa + (wm * 4 + i) * 512 + lane * 8;
            ah[i] = *(const bf16x8*)&sAh[o];
            al[i] = *(const bf16x8*)&sAl[o];
        }
#pragma unroll
        for (int j = 0; j < 2; j++) {
            const int o = sb + (wn * 2 + j) * 512 + lane * 8;
            bh[j] = *(const bf16x8*)&sBh[o];
            bl[j] = *(const bf16x8*)&sBl[o];
        }
        if (stage_c >= 0) STAGE(stage_c);        // writes slot (c-1)%3, sealed prev phase
        __builtin_amdgcn_s_setprio(1);
        // no manual lgkmcnt: compiler emits fine-grained lgkmcnt(N) per operand
        // (tracked plain loads), so MFMAs start on first operand arrival.
#pragma unroll
        for (int i = 0; i < 4; i++)
#pragma unroll
            for (int j = 0; j < 2; j++) {
                acc[i][j] = __builtin_amdgcn_mfma_f32_32x32x16_bf16(ah[i], bh[j], acc[i][j], 0, 0, 0);
                acc[i][j] = __builtin_amdgcn_mfma_f32_32x32x16_bf16(ah[i], bl[j], acc[i][j], 0, 0, 0);
                acc[i][j] = __builtin_amdgcn_mfma_f32_32x32x16_bf16(al[i], bh[j], acc[i][j], 0, 0, 0);
            }
        __builtin_amdgcn_s_setprio(0);
        if (drain == 6)      asm volatile("s_waitcnt vmcnt(6)" ::: "memory");
        else if (drain == 0) asm volatile("s_waitcnt vmcnt(0)" ::: "memory");
        if (drain >= 0) {
            asm volatile("s_waitcnt lgkmcnt(0)" ::: "memory");   // WAR seal before barrier
            asm volatile("s_barrier" ::: "memory");
        }
    };

    // prologue: fill 2 of 3 slots, wait for chunk 0 only (6 stay in flight)
    STAGE(0); STAGE(1);
    asm volatile("s_waitcnt vmcnt(6)" ::: "memory");
    asm volatile("s_barrier" ::: "memory");

    for (int c = 0; c < KB - 2; ++c) PHASE(c, c + 2, 6);
    PHASE(KB - 2, -1, 0);
    PHASE(KB - 1, -1, -1);

    // epilogue: C/D layout col=lane&31, row=(r&3)+8*(r>>2)+4*half (HW-verified r4)
    const int KC = g.ldc >> 4;
#pragma unroll
    for (int j = 0; j < 2; j++) {
        const int col = bn + (wn * 2 + j) * 32 + l31;
        if (col < g.Nreal) {
            const float bv = g.bias[col];
#pragma unroll
            for (int i = 0; i < 4; i++) {
#pragma unroll
                for (int r = 0; r < 16; r++) {
                    const int row = bm + (wm * 4 + i) * 32 + (r & 3) + 8 * (r >> 2) + 4 * half;
                    float v = acc[i][j][r] + bv;
                    if (g.mode == 1) {
                        v = fmaxf(v, 0.f);
                        ushort h, l;
                        split1(v, h, l);
                        const size_t chunk = (size_t)(row >> 5) * KC + (col >> 4);
                        const size_t adr = chunk * 512
                            + (size_t)((row & 31) + 32 * ((col >> 3) & 1)) * 8 + (col & 7);
                        g.Ch[adr] = h;
                        g.Cl[adr] = l;
                    } else {
                        g.Cf[(size_t)row * g.ldc + col] = v;
                    }
                }
            }
        }
    }
}

// ------------- fused per-row softmax stats for both branches -------------
// v15: SINGLE global read pass -- each thread's slice (<=2 float4) is held in
// registers; max-reduce, then sum-of-exp recomputed FROM REGISTERS (old code
// re-read the row). Halves memory passes and barrier count.
__global__ void softmax_stats2(const float* __restrict__ Zo, const float* __restrict__ Za,
                               const int* __restrict__ mc,
                               float* __restrict__ mxo, float* __restrict__ smo,
                               float* __restrict__ mxa, float* __restrict__ sma)
{
    const int r = blockIdx.x;
    if (r >= mc[0]) return;
    __shared__ float red[256];
    const int t = threadIdx.x;
#pragma unroll
    for (int br = 0; br < 2; br++) {
        const float* Z = br ? Za : Zo;
        const int ncols = br ? Aq : Oq;
        float* mx = br ? mxa : mxo;
        float* sm = br ? sma : smo;
        const float4* row = (const float4*)(Z + (size_t)r * ncols);
        const int n4 = ncols >> 2;          // 400 (O) / 100 (A), both <= 512
        float4 v0, v1;
        const bool h0 = t < n4;
        const bool h1 = t + 256 < n4;
        float m = -INFINITY;
        if (h0) { v0 = row[t];       m = fmaxf(fmaxf(v0.x, v0.y), fmaxf(v0.z, v0.w)); }
        if (h1) { v1 = row[t + 256]; m = fmaxf(m, fmaxf(fmaxf(v1.x, v1.y), fmaxf(v1.z, v1.w))); }
        red[t] = m;
        __syncthreads();
        for (int s = 128; s > 0; s >>= 1) {
            if (t < s) red[t] = fmaxf(red[t], red[t + s]);
            __syncthreads();
        }
        m = red[0];
        __syncthreads();
        float su = 0.f;
        if (h0) su  = expf(v0.x - m) + expf(v0.y - m) + expf(v0.z - m) + expf(v0.w - m);
        if (h1) su += expf(v1.x - m) + expf(v1.y - m) + expf(v1.z - m) + expf(v1.w - m);
        red[t] = su;
        __syncthreads();
        for (int s = 128; s > 0; s >>= 1) {
            if (t < s) red[t] += red[t + s];
            __syncthreads();
        }
        if (t == 0) { mx[r] = m; sm[r] = red[0]; }
        __syncthreads();
    }
}

// ------------- fused argmax + output gather (one block per label) -------------
__global__ void argmax_gather(
    const float* __restrict__ Zo, const float* __restrict__ Za,
    const float* __restrict__ mxo, const float* __restrict__ smo,
    const float* __restrict__ mxa, const float* __restrict__ sma,
    const int* __restrict__ label_img, const int* __restrict__ num_descs,
    const int* __restrict__ obj_labels, const int* __restrict__ att_labels,
    const int* __restrict__ off, float* __restrict__ out)
{
    const int l = blockIdx.x;
    const int b = label_img[l];
    const int nd = num_descs[b];
    const int r0 = off[b];
    const int t = threadIdx.x;           // 0..255

    __shared__ float ss[128];
    __shared__ int   si[128];
    if (t < 128) {
        float score = -INFINITY;
        if (t < Nq && t < nd) {
            const int r = r0 + t;
            const float po = expf(Zo[(size_t)r * Oq + obj_labels[l]] - mxo[r]) / smo[r];
            const float pa = expf(Za[(size_t)r * Aq + att_labels[l]] - mxa[r]) / sma[r];
            score = po * pa;
        }
        ss[t] = score;
        si[t] = t;
    }
    __syncthreads();
    for (int s = 64; s > 0; s >>= 1) {
        if (t < s) {
            const float s2 = ss[t + s];
            const int   i2 = si[t + s];
            // first-max tie-break; all -inf -> index 0
            if (s2 > ss[t] || (s2 == ss[t] && i2 < si[t])) { ss[t] = s2; si[t] = i2; }
        }
        __syncthreads();
    }
    const int r = r0 + si[0];

    {
        const float mo = mxo[r];
        const float iso = 1.0f / smo[r];
        const float4* zo4 = (const float4*)(Zo + (size_t)r * Oq);
        float4* oo4 = (float4*)(out + (size_t)l * Oq);
        for (int c = t; c < (Oq >> 2); c += 256) {
            const float4 v = zo4[c];
            float4 w;
            w.x = expf(v.x - mo) * iso;
            w.y = expf(v.y - mo) * iso;
            w.z = expf(v.z - mo) * iso;
            w.w = expf(v.w - mo) * iso;
            oo4[c] = w;
        }
    }
    {
        const float ma = mxa[r];
        const float isa = 1.0f / sma[r];
        const float4* za4 = (const float4*)(Za + (size_t)r * Aq);
        float4* oa4 = (float4*)(out + (size_t)Lq * Oq + (size_t)l * Aq);
        for (int c = t; c < (Aq >> 2); c += 256) {
            const float4 v = za4[c];
            float4 w;
            w.x = expf(v.x - ma) * isa;
            w.y = expf(v.y - ma) * isa;
            w.z = expf(v.z - ma) * isa;
            w.w = expf(v.w - ma) * isa;
            oa4[c] = w;
        }
    }
}

extern "C" void kernel_launch(void* const* d_in, const int* in_sizes, int n_in,
                              void* d_out, int out_size, void* d_ws, size_t ws_size,
                              hipStream_t stream)
{
    const float* x          = (const float*)d_in[0];
    const int*   num_descs  = (const int*)d_in[1];
    const int*   label_img  = (const int*)d_in[2];
    const int*   obj_labels = (const int*)d_in[3];
    const int*   att_labels = (const int*)d_in[4];
    const float* w1o = (const float*)d_in[5];  const float* b1o = (const float*)d_in[6];
    const float* w2o = (const float*)d_in[7];  const float* b2o = (const float*)d_in[8];
    const float* w3o = (const float*)d_in[9];  const float* b3o = (const float*)d_in[10];
    const float* w1a = (const float*)d_in[11]; const float* b1a = (const float*)d_in[12];
    const float* w2a = (const float*)d_in[13]; const float* b2a = (const float*)d_in[14];
    const float* w3a = (const float*)d_in[15]; const float* b3a = (const float*)d_in[16];
    float* out = (float*)d_out;

    // ---- workspace carve with lifetime-based aliasing ----
    char* p = (char*)d_ws;
    auto carve = [&](size_t bytes) { char* q = p; p += (bytes + 255) & ~(size_t)255; return q; };

    char* bufA = carve((size_t)Mq * Dq * 2 * 2);            // xh|xl -> h2{o,a}{h,l}
    char* bufB = carve((size_t)Mq * Hq * 2 * 2 * 2);        // h1{o,a}{h,l} -> z3o|z3a
    ushort* w1oth = (ushort*)carve((size_t)Hq * Dq * 2);  ushort* w1otl = (ushort*)carve((size_t)Hq * Dq * 2);
    ushort* w1ath = (ushort*)carve((size_t)Hq * Dq * 2);  ushort* w1atl = (ushort*)carve((size_t)Hq * Dq * 2);
    ushort* w2oth = (ushort*)carve((size_t)Hq * Hq * 2);  ushort* w2otl = (ushort*)carve((size_t)Hq * Hq * 2);
    ushort* w2ath = (ushort*)carve((size_t)Hq * Hq * 2);  ushort* w2atl = (ushort*)carve((size_t)Hq * Hq * 2);
    ushort* w3oth = (ushort*)carve((size_t)OqP * Hq * 2); ushort* w3otl = (ushort*)carve((size_t)OqP * Hq * 2);
    ushort* w3ath = (ushort*)carve((size_t)AqP * Hq * 2); ushort* w3atl = (ushort*)carve((size_t)AqP * Hq * 2);
    float* mxo = (float*)carve(Mq * 4); float* smo = (float*)carve(Mq * 4);
    float* mxa = (float*)carve(Mq * 4); float* sma = (float*)carve(Mq * 4);
    int* off    = (int*)carve(Bq * 4);
    int* mc     = (int*)carve(4 * 4);
    int* rowmap = (int*)carve(Mq * 4);

    // aliased views
    ushort* xh = (ushort*)bufA;
    ushort* xl = xh + (size_t)Mq * Dq;
    ushort* h2oh = (ushort*)bufA;                    // x dead after L1
    ushort* h2ol = h2oh + (size_t)Mq * Hq;
    ushort* h2ah = h2ol + (size_t)Mq * Hq;
    ushort* h2al = h2ah + (size_t)Mq * Hq;
    ushort* h1oh = (ushort*)bufB;
    ushort* h1ol = h1oh + (size_t)Mq * Hq;
    ushort* h1ah = h1ol + (size_t)Mq * Hq;
    ushort* h1al = h1ah + (size_t)Mq * Hq;
    float* z3o = (float*)bufB;                       // h1 dead after L2
    float* z3a = z3o + (size_t)Mq * Oq;

    // ---- preprocessing ----
    build_offsets<<<1, 128, 0, stream>>>(num_descs, off, mc, rowmap);

    {   // merged: x gather+split + 6-segment weight transpose+split, one dispatch
        TSegs ts;
        int base = 0;
        auto seg = [&](const float* W, ushort* Th, ushort* Tl, int K, int N, int Npad) {
            TSeg s; s.W = W; s.Th = Th; s.Tl = Tl; s.K = K; s.N = N;
            s.gx = Npad / 32; s.base = base; base += (Npad / 32) * (K / 32); return s;
        };
        ts.s[0] = seg(w1o, w1oth, w1otl, Dq, Hq, Hq);
        ts.s[1] = seg(w1a, w1ath, w1atl, Dq, Hq, Hq);
        ts.s[2] = seg(w2o, w2oth, w2otl, Hq, Hq, Hq);
        ts.s[3] = seg(w2a, w2ath, w2atl, Hq, Hq, Hq);
        ts.s[4] = seg(w3o, w3oth, w3otl, Hq, Oq, OqP);
        ts.s[5] = seg(w3a, w3ath, w3atl, Hq, Aq, AqP);
        const int nsplit = (Mq / 32) * (Dq / 64);            // 12800
        prep_all<<<nsplit + base, 256, 0, stream>>>(x, rowmap, mc, xh, xl, ts, nsplit);
    }

    // flat 1D grids over (by x combined-ct); worst-case ny = Mq/256 = 50.
    // Kernel swizzles the runtime-active range (XCD-chunked, by outer -> A shared).
    // ---- L1: h1 = relu(x @ w1 + b1), both branches fused ----
    {
        GArgs go = { xh, xl, w1oth, w1otl, b1o, nullptr, h1oh, h1ol, Dq, Hq, Hq, Hq, 1 };
        GArgs ga = { xh, xl, w1ath, w1atl, b1a, nullptr, h1ah, h1al, Dq, Hq, Hq, Hq, 1 };
        gemm_split<<<16 * (Mq / 256), 256, 0, stream>>>(go, ga, mc, 8, 16);
    }
    // ---- L2: h2 = relu(h1 @ w2 + b2) ----
    {
        GArgs go = { h1oh, h1ol, w2oth, w2otl, b2o, nullptr, h2oh, h2ol, Hq, Hq, Hq, Hq, 1 };
        GArgs ga = { h1ah, h1al, w2ath, w2atl, b2a, nullptr, h2ah, h2al, Hq, Hq, Hq, Hq, 1 };
        gemm_split<<<16 * (Mq / 256), 256, 0, stream>>>(go, ga, mc, 8, 16);
    }
    // ---- L3: z3 = h2 @ w3 + b3 (fp32 row-major out) ----
    {
        GArgs go = { h2oh, h2ol, w3oth, w3otl, b3o, z3o, nullptr, nullptr, Hq, OqP, Oq, Oq, 0 };
        GArgs ga = { h2ah, h2al, w3ath, w3atl, b3a, z3a, nullptr, nullptr, Hq, AqP, Aq, Aq, 0 };
        gemm_split<<<(OqP / 128 + AqP / 128) * (Mq / 256), 256, 0, stream>>>(go, ga, mc,
                                                                            OqP / 128,
                                                                            OqP / 128 + AqP / 128);
    }

    // ---- epilogue ----
    softmax_stats2<<<Mq, 256, 0, stream>>>(z3o, z3a, mc, mxo, smo, mxa, sma);
    argmax_gather<<<Lq, 256, 0, stream>>>(z3o, z3a, mxo, smo, mxa, sma,
                                          label_img, num_descs, obj_labels, att_labels, off, out);
}